// Round 2
// 526.406 us; speedup vs baseline: 1.0263x; 1.0263x over previous
//
#include <hip/hip_runtime.h>
#include <hip/hip_bf16.h>

// MoBoAlignerAttention on MI355X — round 5 (round-4 compile fix).
// phase1_a: single-wave, barrier-free wave-synchronous scan. 64 threads
// (1 wave) per batch, 16 j/lane; LDS q-exchange ordered by lgkmcnt(0) only
// (no barrier -> global a-stores never drained inside the 384-step loop);
// +4/16 pad swizzle on the q buffer (all 32 banks per b128 access); cp
// columns prefetched 2 steps ahead via unroll-by-3 with named float4 regs.
// Fix vs round 4: macro takes all eight float4 names explicitly (no ## with
// a member-access suffix -- `CPU##0.x` lexes 0.x as one pp-number token).
//
// Pipeline:
//  conv_bf16   : mel f32 -> melh bf16 [n][j][d]
//  conv_encT   : enc f32 -> ench bf16 [n][k][d]  +  encT bf16 [n][d][k]
//  gemm_mfma   : scores = melh @ ench^T / sqrt(512)         (bf16 MFMA)
//  gen_T       : JAX Threefry-2x32 (partitionable) uniform
//  softmax_rows: s_alignment -> d_out
//  cond_prob2  : cp = e / (window_19(e)+1e-8), k-major cpT
//  phase1_a    : a_k[j] = sum_{t=j-20..j-2} a_{k-1}[t]*cp_{k-1}[t]  (1 wave/n)
//  phase2_B    : B[j,k] = sum_{d=2..19} a[j-d,k]*W_{20-d}(j,k)
//  transpose_B : BT -> d_out B slot (f32) + Bh bf16 [n][j][k]
//  gemm_mfma   : att = Bh @ encT^T                          (bf16 MFMA)

#define NB 32
#define TD 1024
#define TE 384
#define DM 512

typedef __attribute__((ext_vector_type(8))) short bf16x8;
typedef __attribute__((ext_vector_type(4))) float f32x4;

// f32 -> bf16 round-to-nearest-even
__device__ __forceinline__ ushort f2bf(float f) {
  unsigned u = __float_as_uint(f);
  return (ushort)((u + 0x7FFFu + ((u >> 16) & 1u)) >> 16);
}

// ---------------------------------------------------------------- threefry
__device__ __forceinline__ void tf_round(unsigned &x0, unsigned &x1, int r) {
  x0 += x1;
  x1 = (x1 << r) | (x1 >> (32 - r));
  x1 ^= x0;
}

__device__ __forceinline__ void threefry2x32(unsigned c0, unsigned c1,
                                             unsigned &o0, unsigned &o1) {
  const unsigned k0 = 0u, k1 = 1234u;
  const unsigned k2 = 0u ^ 1234u ^ 0x1BD11BDAu;
  unsigned x0 = c0 + k0, x1 = c1 + k1;
  tf_round(x0, x1, 13); tf_round(x0, x1, 15); tf_round(x0, x1, 26); tf_round(x0, x1, 6);
  x0 += k1; x1 += k2 + 1u;
  tf_round(x0, x1, 17); tf_round(x0, x1, 29); tf_round(x0, x1, 16); tf_round(x0, x1, 24);
  x0 += k2; x1 += k0 + 2u;
  tf_round(x0, x1, 13); tf_round(x0, x1, 15); tf_round(x0, x1, 26); tf_round(x0, x1, 6);
  x0 += k0; x1 += k1 + 3u;
  tf_round(x0, x1, 17); tf_round(x0, x1, 29); tf_round(x0, x1, 16); tf_round(x0, x1, 24);
  x0 += k1; x1 += k2 + 4u;
  tf_round(x0, x1, 13); tf_round(x0, x1, 15); tf_round(x0, x1, 26); tf_round(x0, x1, 6);
  x0 += k2; x1 += k0 + 5u;
  o0 = x0; o1 = x1;
}

__device__ __forceinline__ float tf_uniform(unsigned bits) {
  return __uint_as_float((bits >> 9) | 0x3F800000u) - 1.0f;
}

__global__ __launch_bounds__(256) void gen_T(float *__restrict__ Tbuf) {
  int i = blockIdx.x * blockDim.x + threadIdx.x;  // 0..12287
  if (i >= NB * TE) return;
  unsigned o0, o1;
  threefry2x32(0u, (unsigned)i, o0, o1);
  Tbuf[i] = tf_uniform(o0 ^ o1) + 0.5f;  // T = u*(1.5-0.5)+0.5
}

// ---------------------------------------------------------------- f32 -> bf16 (8 elems/thread)
__global__ __launch_bounds__(256) void conv_bf16(const float *__restrict__ src,
                                                 ushort *__restrict__ dst) {
  const size_t i = ((size_t)blockIdx.x * 256 + threadIdx.x) * 8;
  float4 a = *(const float4 *)(src + i);
  float4 b = *(const float4 *)(src + i + 4);
  uint4 o;
  o.x = (unsigned)f2bf(a.x) | ((unsigned)f2bf(a.y) << 16);
  o.y = (unsigned)f2bf(a.z) | ((unsigned)f2bf(a.w) << 16);
  o.z = (unsigned)f2bf(b.x) | ((unsigned)f2bf(b.y) << 16);
  o.w = (unsigned)f2bf(b.z) | ((unsigned)f2bf(b.w) << 16);
  *(uint4 *)(dst + i) = o;
}

// ---------------------------------------------------------------- enc -> ench + encT
__global__ __launch_bounds__(256) void conv_encT(const float *__restrict__ enc,
                                                 ushort *__restrict__ ench,
                                                 ushort *__restrict__ encT) {
  const int n = blockIdx.z;
  const int d0 = blockIdx.x * 32;
  const int k0 = blockIdx.y * 32;
  __shared__ ushort t[32][33];
  const int row = threadIdx.x >> 3;      // k within tile
  const int c4 = (threadIdx.x & 7) * 4;  // d within tile
  float4 v = *(const float4 *)(enc + ((size_t)n * TE + k0 + row) * DM + d0 + c4);
  ushort4 e;
  e.x = f2bf(v.x); e.y = f2bf(v.y); e.z = f2bf(v.z); e.w = f2bf(v.w);
  t[row][c4 + 0] = e.x; t[row][c4 + 1] = e.y;
  t[row][c4 + 2] = e.z; t[row][c4 + 3] = e.w;
  *(ushort4 *)(ench + ((size_t)n * TE + k0 + row) * DM + d0 + c4) = e;
  __syncthreads();
  const int dr = threadIdx.x >> 3;       // d within tile
  const int kc = (threadIdx.x & 7) * 4;  // k within tile
  ushort4 o;
  o.x = t[kc + 0][dr]; o.y = t[kc + 1][dr];
  o.z = t[kc + 2][dr]; o.w = t[kc + 3][dr];
  *(ushort4 *)(encT + ((size_t)n * DM + d0 + dr) * TE + k0 + kc) = o;
}

// ---------------------------------------------------------------- bf16 MFMA GEMM
// C[m][n] = scale * sum_k A[m][k]*B[n][k]   (both operands K-contiguous)
// 128x128 tile, 4 waves (2x2), each wave 4x4 16x16x32 MFMA tiles, BK=32.
__global__ __launch_bounds__(256) void gemm_bf16_mfma(
    const ushort *__restrict__ Ag, const ushort *__restrict__ Bg,
    float *__restrict__ Cg, int K, int N, size_t sA, size_t sB, size_t sC,
    float scale) {
  const int nb = blockIdx.z;
  const int n0 = blockIdx.x * 128;
  const int m0 = blockIdx.y * 128;
  const int tid = threadIdx.x;
  const int wave = tid >> 6, lane = tid & 63;
  const int wm = (wave >> 1) * 64, wn = (wave & 1) * 64;
  const int fr = lane & 15, quad = lane >> 4;
  const ushort *A = Ag + nb * sA + (size_t)m0 * K;
  const ushort *B = Bg + nb * sB + (size_t)n0 * K;
  __shared__ ushort As[128 * 32];
  __shared__ ushort Bs[128 * 32];
  f32x4 acc[4][4];
#pragma unroll
  for (int i = 0; i < 4; ++i)
#pragma unroll
    for (int c = 0; c < 4; ++c) acc[i][c] = (f32x4){0.f, 0.f, 0.f, 0.f};

  const int srow = tid >> 1;        // 0..127
  const int scol = (tid & 1) * 16;  // 0 or 16 (ushort offset)
  for (int kb = 0; kb < K; kb += 32) {
    uint4 av0 = *(const uint4 *)(A + (size_t)srow * K + kb + scol);
    uint4 av1 = *(const uint4 *)(A + (size_t)srow * K + kb + scol + 8);
    uint4 bv0 = *(const uint4 *)(B + (size_t)srow * K + kb + scol);
    uint4 bv1 = *(const uint4 *)(B + (size_t)srow * K + kb + scol + 8);
    __syncthreads();
    *(uint4 *)(&As[srow * 32 + scol]) = av0;
    *(uint4 *)(&As[srow * 32 + scol + 8]) = av1;
    *(uint4 *)(&Bs[srow * 32 + scol]) = bv0;
    *(uint4 *)(&Bs[srow * 32 + scol + 8]) = bv1;
    __syncthreads();
    bf16x8 af[4], bfv[4];
#pragma unroll
    for (int i = 0; i < 4; ++i)
      af[i] = *(const bf16x8 *)(&As[(wm + i * 16 + fr) * 32 + quad * 8]);
#pragma unroll
    for (int c = 0; c < 4; ++c)
      bfv[c] = *(const bf16x8 *)(&Bs[(wn + c * 16 + fr) * 32 + quad * 8]);
#pragma unroll
    for (int i = 0; i < 4; ++i)
#pragma unroll
      for (int c = 0; c < 4; ++c)
        acc[i][c] = __builtin_amdgcn_mfma_f32_16x16x32_bf16(af[i], bfv[c],
                                                            acc[i][c], 0, 0, 0);
  }
  float *Cb = Cg + nb * sC;
#pragma unroll
  for (int i = 0; i < 4; ++i)
#pragma unroll
    for (int c = 0; c < 4; ++c)
#pragma unroll
      for (int r = 0; r < 4; ++r)
        Cb[(size_t)(m0 + wm + i * 16 + quad * 4 + r) * N + n0 + wn + c * 16 + fr] =
            acc[i][c][r] * scale;
}

// ---------------------------------------------------------------- softmax
__global__ __launch_bounds__(64) void softmax_rows(
    const float *__restrict__ scores, float *__restrict__ out1) {
  const int row = blockIdx.x;  // n*TD + j
  const int n = row >> 10;
  const int j = row & 1023;
  const int tid = threadIdx.x;
  const float *s = scores + (size_t)row * TE;
  float v[6];
#pragma unroll
  for (int i = 0; i < 6; ++i) v[i] = s[tid + 64 * i];
  float m = v[0];
#pragma unroll
  for (int i = 1; i < 6; ++i) m = fmaxf(m, v[i]);
#pragma unroll
  for (int off = 32; off; off >>= 1) m = fmaxf(m, __shfl_xor(m, off));
  float e[6], sum = 0.f;
#pragma unroll
  for (int i = 0; i < 6; ++i) { e[i] = __expf(v[i] - m); sum += e[i]; }
#pragma unroll
  for (int off = 32; off; off >>= 1) sum += __shfl_xor(sum, off);
  const float r = 1.0f / sum;
  float *dst = out1 + (size_t)n * (2 * TD * TE) + (size_t)j * TE;
#pragma unroll
  for (int i = 0; i < 6; ++i) dst[tid + 64 * i] = e[i] * r;
}

// ---------------------------------------------------------------- cond_prob (parallel)
__global__ __launch_bounds__(256) void cond_prob2(
    const float *__restrict__ scores, const float *__restrict__ Tbuf,
    float *__restrict__ cpT) {
  const int n = blockIdx.z;
  const int j0 = blockIdx.y * 64;
  const int k0 = blockIdx.x * 64;
  const int tid = threadIdx.x;
  __shared__ float eL[82][65];

  {
    const int c4 = (tid & 15) * 4;
    const int r0 = tid >> 4;  // 0..15
    float4 tv = *(const float4 *)(Tbuf + n * TE + k0 + c4);
    const float it0 = 1.0f / tv.x, it1 = 1.0f / tv.y, it2 = 1.0f / tv.z,
                it3 = 1.0f / tv.w;
#pragma unroll
    for (int p = 0; p < 6; ++p) {
      const int r = r0 + p * 16;
      if (r < 82) {
        const int j = j0 + r;
        float4 s;
        if (j < TD) {
          s = *(const float4 *)(scores + ((size_t)n * TD + j) * TE + k0 + c4);
          s.x = __expf(s.x * it0); s.y = __expf(s.y * it1);
          s.z = __expf(s.z * it2); s.w = __expf(s.w * it3);
        } else {
          s = make_float4(0.f, 0.f, 0.f, 0.f);
        }
        eL[r][c4 + 0] = s.x; eL[r][c4 + 1] = s.y;
        eL[r][c4 + 2] = s.z; eL[r][c4 + 3] = s.w;
      }
    }
  }
  __syncthreads();

  const int k = tid & 63;
  const int jl0 = (tid >> 6) * 16;
  float e_r[35];
#pragma unroll
  for (int t = 0; t < 35; ++t) e_r[t] = eL[jl0 + t][k];
  float win = 0.f;
#pragma unroll
  for (int t = 15; t <= 33; ++t) win += e_r[t];
  float cp[16];
#pragma unroll
  for (int jl = 15; jl >= 0; --jl) {
    cp[jl] = e_r[jl] / (win + 1e-8f);
    if (jl > 0) win += e_r[jl - 1] - e_r[jl + 18];
  }
  float *dst = cpT + ((size_t)n * TE + k0 + k) * TD + j0 + jl0;
#pragma unroll
  for (int q = 0; q < 4; ++q)
    *(float4 *)(dst + q * 4) =
        make_float4(cp[q * 4], cp[q * 4 + 1], cp[q * 4 + 2], cp[q * 4 + 3]);
}

// ---------------------------------------------------------------- phase 1 (a scan)
// Single wave per batch n. 16 j per lane. Wave-synchronous LDS exchange of
// q = a*cp (24-float backward halo), no __syncthreads -> global a-stores are
// never drained inside the 384-step serial loop.
// LDS layout: logical J = j+24 in [0,1048) mapped to phys = J + (J>>4)*4
// (+4 floats of pad per 16) so every ds_read/write_b128 covers all 32 banks.
#define P1PH(J) ((J) + (((J) >> 4) << 2))

#define P1_BODY(CU0, CU1, CU2, CU3, CL0, CL1, CL2, CL3, kk)                   \
  {                                                                           \
    /* prefetch cp column used at step (kk)+2 (column shift: col(k)=k-1) */   \
    const int pc = ((kk) + 1 < TE) ? ((kk) + 1) : (TE - 1);                   \
    const float *pp = cpn + (size_t)pc * TD + j0;                             \
    CL0 = *(const float4 *)(pp);                                              \
    CL1 = *(const float4 *)(pp + 4);                                          \
    CL2 = *(const float4 *)(pp + 8);                                          \
    CL3 = *(const float4 *)(pp + 12);                                         \
    float4 q0 = make_float4(a[0] * CU0.x, a[1] * CU0.y,                       \
                            a[2] * CU0.z, a[3] * CU0.w);                      \
    float4 q1 = make_float4(a[4] * CU1.x, a[5] * CU1.y,                       \
                            a[6] * CU1.z, a[7] * CU1.w);                      \
    float4 q2 = make_float4(a[8] * CU2.x, a[9] * CU2.y,                       \
                            a[10] * CU2.z, a[11] * CU2.w);                    \
    float4 q3 = make_float4(a[12] * CU3.x, a[13] * CU3.y,                     \
                            a[14] * CU3.z, a[15] * CU3.w);                    \
    *(float4 *)(w01p) = q0;                                                   \
    *(float4 *)(w01p + 4) = q1;                                               \
    *(float4 *)(w23p) = q2;                                                   \
    *(float4 *)(w23p + 4) = q3;                                               \
    asm volatile("s_waitcnt lgkmcnt(0)" ::: "memory");                        \
    float4 h0 = *(const float4 *)(r0p);                                       \
    float4 h1 = *(const float4 *)(r0p + 4);                                   \
    float4 h2 = *(const float4 *)(r0p + 8);                                   \
    float4 h3 = *(const float4 *)(r0p + 12);                                  \
    float4 h4 = *(const float4 *)(r1p);                                       \
    float4 h5 = *(const float4 *)(r1p + 4);                                   \
    float w[38];                                                              \
    w[0] = h0.x;  w[1] = h0.y;  w[2] = h0.z;  w[3] = h0.w;                    \
    w[4] = h1.x;  w[5] = h1.y;  w[6] = h1.z;  w[7] = h1.w;                    \
    w[8] = h2.x;  w[9] = h2.y;  w[10] = h2.z; w[11] = h2.w;                   \
    w[12] = h3.x; w[13] = h3.y; w[14] = h3.z; w[15] = h3.w;                   \
    w[16] = h4.x; w[17] = h4.y; w[18] = h4.z; w[19] = h4.w;                   \
    w[20] = h5.x; w[21] = h5.y; w[22] = h5.z; w[23] = h5.w;                   \
    w[24] = q0.x; w[25] = q0.y; w[26] = q0.z; w[27] = q0.w;                   \
    w[28] = q1.x; w[29] = q1.y; w[30] = q1.z; w[31] = q1.w;                   \
    w[32] = q2.x; w[33] = q2.y; w[34] = q2.z; w[35] = q2.w;                   \
    w[36] = q3.x; w[37] = q3.y;                                               \
    /* window for j=j0+i is sum w[i+4 .. i+22]; two balanced trees + slides */\
    float t0 = w[4] + w[5], t1 = w[6] + w[7], t2 = w[8] + w[9];               \
    float t3 = w[10] + w[11], t4 = w[12] + w[13], t5 = w[14] + w[15];         \
    float t6 = w[16] + w[17], t7 = w[18] + w[19], t8 = w[20] + w[21];         \
    float s0 = (((t0 + t1) + (t2 + t3)) + ((t4 + t5) + (t6 + t7))) +          \
               (t8 + w[22]);                                                  \
    a[0] = s0;                                                                \
    s0 += w[23] - w[4];  a[1] = s0;                                           \
    s0 += w[24] - w[5];  a[2] = s0;                                           \
    s0 += w[25] - w[6];  a[3] = s0;                                           \
    s0 += w[26] - w[7];  a[4] = s0;                                           \
    s0 += w[27] - w[8];  a[5] = s0;                                           \
    s0 += w[28] - w[9];  a[6] = s0;                                           \
    s0 += w[29] - w[10]; a[7] = s0;                                           \
    float u4 = w[20] + w[21], u5 = w[22] + w[23], u6 = w[24] + w[25];         \
    float u7 = w[26] + w[27], u8 = w[28] + w[29];                             \
    float s1 = (((t4 + t5) + (t6 + t7)) + ((u4 + u5) + (u6 + u7))) +          \
               (u8 + w[30]);                                                  \
    a[8] = s1;                                                                \
    s1 += w[31] - w[12]; a[9] = s1;                                           \
    s1 += w[32] - w[13]; a[10] = s1;                                          \
    s1 += w[33] - w[14]; a[11] = s1;                                          \
    s1 += w[34] - w[15]; a[12] = s1;                                          \
    s1 += w[35] - w[16]; a[13] = s1;                                          \
    s1 += w[36] - w[17]; a[14] = s1;                                          \
    s1 += w[37] - w[18]; a[15] = s1;                                          \
    float *ao = an + (size_t)(kk)*TD + j0;                                    \
    *(float4 *)(ao) = make_float4(a[0], a[1], a[2], a[3]);                    \
    *(float4 *)(ao + 4) = make_float4(a[4], a[5], a[6], a[7]);                \
    *(float4 *)(ao + 8) = make_float4(a[8], a[9], a[10], a[11]);              \
    *(float4 *)(ao + 12) = make_float4(a[12], a[13], a[14], a[15]);           \
    asm volatile("" ::: "memory");                                            \
  }

__global__ __launch_bounds__(64) void phase1_a(
    const float *__restrict__ cpT, float *__restrict__ aT) {
  const int n = blockIdx.x;
  const int L = threadIdx.x;  // 0..63, one wave
  const int j0 = L * 16;
  __shared__ __align__(16) float qbuf[1320];  // 66 groups * 20 floats

  // zero the 24-float logical pad (j in [-24,-1] -> J in [0,24))
  if (L < 24) qbuf[P1PH(L)] = 0.f;

  const float *cpn = cpT + (size_t)n * TE * TD;
  float *an = aT + (size_t)n * TE * TD;

  // lane-local LDS pointers (all b128-aligned, each instr covers 32 banks)
  const int Jw = j0 + 24, Jw2 = j0 + 32, Jr = j0, Jr2 = j0 + 16;
  float *w01p = &qbuf[P1PH(Jw)];
  float *w23p = &qbuf[P1PH(Jw2)];
  const float *r0p = &qbuf[P1PH(Jr)];
  const float *r1p = &qbuf[P1PH(Jr2)];

  float a[16];
#pragma unroll
  for (int i = 0; i < 16; ++i) a[i] = 0.f;
  if (L == 0) a[0] = 1.f;

  // prologue: steps 0 and 1 both use cp column 0 (reference's col shift)
  float4 cpA0, cpA1, cpA2, cpA3, cpB0, cpB1, cpB2, cpB3, cpC0, cpC1, cpC2, cpC3;
  {
    const float *p0 = cpn + j0;
    cpA0 = *(const float4 *)(p0);
    cpA1 = *(const float4 *)(p0 + 4);
    cpA2 = *(const float4 *)(p0 + 8);
    cpA3 = *(const float4 *)(p0 + 12);
    cpB0 = cpA0; cpB1 = cpA1; cpB2 = cpA2; cpB3 = cpA3;
  }

  for (int k = 0; k < TE; k += 3) {  // TE = 384 = 3*128
    P1_BODY(cpA0, cpA1, cpA2, cpA3, cpC0, cpC1, cpC2, cpC3, k);
    P1_BODY(cpB0, cpB1, cpB2, cpB3, cpA0, cpA1, cpA2, cpA3, k + 1);
    P1_BODY(cpC0, cpC1, cpC2, cpC3, cpB0, cpB1, cpB2, cpB3, k + 2);
  }
}

// ---------------------------------------------------------------- phase 2 (B)
__global__ __launch_bounds__(256) void phase2_B(
    const float *__restrict__ cpT, const float *__restrict__ aT,
    float *__restrict__ BT) {
  const int k = blockIdx.x;
  const int n = blockIdx.y;
  const int tid = threadIdx.x;
  const float *cpc = cpT + ((size_t)n * TE + k) * TD;
  const float *ac = aT + ((size_t)n * TE + k) * TD;
  __shared__ float a_l[20 + TD];
  __shared__ float cp_l[TD + 24];
  float4 av = *(const float4 *)(ac + tid * 4);
  *(float4 *)(&a_l[20 + tid * 4]) = av;
  float4 cv = *(const float4 *)(cpc + tid * 4);
  if (tid == 255) cv.w = 0.f;  // cp[1023] never contributes (clamp rule)
  *(float4 *)(&cp_l[tid * 4]) = cv;
  if (tid < 20) a_l[tid] = 0.f;
  if (tid < 24) cp_l[TD + tid] = 0.f;
  __syncthreads();
  const int j0 = tid * 4;
  float ar[21], cpr[21];
#pragma unroll
  for (int t = 0; t < 21; ++t) ar[t] = a_l[20 + j0 - 19 + t];
#pragma unroll
  for (int t = 0; t < 21; ++t) cpr[t] = cp_l[j0 + t];
  float Bo[4];
#pragma unroll
  for (int i = 0; i < 4; ++i) {
    float W = 0.f, acc2 = 0.f;
#pragma unroll
    for (int d = 19; d >= 2; --d) {
      W += cpr[i + 19 - d];
      acc2 = fmaf(ar[19 + i - d], W, acc2);
    }
    Bo[i] = acc2;
  }
  *(float4 *)(BT + ((size_t)n * TE + k) * TD + j0) =
      make_float4(Bo[0], Bo[1], Bo[2], Bo[3]);
}

// ---------------------------------------------------------------- transpose (+ bf16 copy)
__global__ __launch_bounds__(256) void transpose_B(
    const float *__restrict__ BT, float *__restrict__ out1,
    ushort *__restrict__ Bh) {
  __shared__ float tile[32][33];
  const int n = blockIdx.z;
  const int k0 = blockIdx.x * 32;
  const int j0 = blockIdx.y * 32;
  const int tx = threadIdx.x & 31;
  const int ty = threadIdx.x >> 5;  // 0..7
  const float *src = BT + (size_t)n * TE * TD;
#pragma unroll
  for (int r = 0; r < 4; ++r) {
    const int kk = ty + r * 8;
    tile[kk][tx] = src[(size_t)(k0 + kk) * TD + j0 + tx];
  }
  __syncthreads();
  float *dst = out1 + (size_t)n * (2 * TD * TE) + (size_t)TD * TE;
#pragma unroll
  for (int r = 0; r < 4; ++r) {
    const int jj = ty + r * 8;
    const float val = tile[tx][jj];
    dst[(size_t)(j0 + jj) * TE + k0 + tx] = val;
    Bh[((size_t)n * TD + j0 + jj) * TE + k0 + tx] = f2bf(val);
  }
}

// ---------------------------------------------------------------- launch
extern "C" void kernel_launch(void *const *d_in, const int *in_sizes, int n_in,
                              void *d_out, int out_size, void *d_ws,
                              size_t ws_size, hipStream_t stream) {
  (void)in_sizes; (void)n_in; (void)out_size; (void)ws_size;
  const float *enc = (const float *)d_in[0];  // [32][384][512]
  const float *mel = (const float *)d_in[1];  // [32][1024][512]
  float *out = (float *)d_out;
  float *out0 = out;                         // att_out [32][1024][512]
  float *out1 = out + (size_t)NB * TD * DM;  // stacked [32][2][1024][384]

  const size_t SZ = (size_t)NB * TD * TE;    // 12,582,912 floats
  float *ws = (float *)d_ws;
  float *ws_scores = ws;       // scores [n][j][k]; later BT
  float *ws_cpT = ws + SZ;     // cond_prob [n][k][j] (holds ench+melh before)
  float *ws_aT = ws + 2 * SZ;  // a [n][k][j] (holds Bh after phase2)
  float *ws_T = ws + 3 * SZ;   // T [n][k]
  ushort *encTb = (ushort *)(ws + 3 * SZ + NB * TE);  // encT bf16 [n][d][k]
  ushort *ench = (ushort *)ws_cpT;                    // bf16 [n][k][d]
  ushort *melh = (ushort *)ws_cpT + (size_t)NB * TE * DM;  // bf16 [n][j][d]
  ushort *Bh = (ushort *)ws_aT;                       // bf16 [n][j][k]
  float *ws_BT = ws_scores;

  conv_bf16<<<(NB * TD * DM) / (256 * 8), 256, 0, stream>>>(mel, melh);
  conv_encT<<<dim3(DM / 32, TE / 32, NB), 256, 0, stream>>>(enc, ench, encTb);
  gen_T<<<48, 256, 0, stream>>>(ws_T);
  gemm_bf16_mfma<<<dim3(TE / 128, TD / 128, NB), 256, 0, stream>>>(
      melh, ench, ws_scores, DM, TE, (size_t)TD * DM, (size_t)TE * DM,
      (size_t)TD * TE, 0.0441941738241592f);
  softmax_rows<<<NB * TD, 64, 0, stream>>>(ws_scores, out1);
  cond_prob2<<<dim3(TE / 64, TD / 64, NB), 256, 0, stream>>>(ws_scores, ws_T, ws_cpT);
  phase1_a<<<NB, 64, 0, stream>>>(ws_cpT, ws_aT);
  phase2_B<<<dim3(TE, NB), 256, 0, stream>>>(ws_cpT, ws_aT, ws_BT);
  transpose_B<<<dim3(TE / 32, TD / 32, NB), 256, 0, stream>>>(ws_BT, out1, Bh);
  gemm_bf16_mfma<<<dim3(DM / 128, TD / 128, NB), 256, 0, stream>>>(
      Bh, encTb, out0, TE, DM, (size_t)TD * TE, (size_t)DM * TE,
      (size_t)TD * DM, 1.0f);
}

// Round 3
// 520.127 us; speedup vs baseline: 1.0387x; 1.0121x over previous
//
#include <hip/hip_runtime.h>
#include <hip/hip_bf16.h>

// MoBoAlignerAttention on MI355X — round 6.
// Change vs round 5 (phase1_a only):
//  * removed the explicit `s_waitcnt lgkmcnt(0)` HW stall; same-wave DS ops
//    execute in program order, so only zero-instruction compiler fences
//    (asm "" ::: "memory") are needed between LDS writes<->reads. The
//    compiler now inserts a minimal lgkmcnt before first use of read data
//    and can fill the LDS round-trip with independent VALU work.
//  * halo read shrunk 24 -> 20 floats (w[0..3] was dead): 5 ds_read_b128.
//  * cp prefetch depth 2 -> 3 (unroll-4, 4 named float4 register sets).
// Everything else identical to round 5.
//
// Pipeline:
//  conv_bf16   : mel f32 -> melh bf16 [n][j][d]
//  conv_encT   : enc f32 -> ench bf16 [n][k][d]  +  encT bf16 [n][d][k]
//  gemm_mfma   : scores = melh @ ench^T / sqrt(512)         (bf16 MFMA)
//  gen_T       : JAX Threefry-2x32 (partitionable) uniform
//  softmax_rows: s_alignment -> d_out
//  cond_prob2  : cp = e / (window_19(e)+1e-8), k-major cpT
//  phase1_a    : a_k[j] = sum_{t=j-20..j-2} a_{k-1}[t]*cp_{k-1}[t]  (1 wave/n)
//  phase2_B    : B[j,k] = sum_{d=2..19} a[j-d,k]*W_{20-d}(j,k)
//  transpose_B : BT -> d_out B slot (f32) + Bh bf16 [n][j][k]
//  gemm_mfma   : att = Bh @ encT^T                          (bf16 MFMA)

#define NB 32
#define TD 1024
#define TE 384
#define DM 512

typedef __attribute__((ext_vector_type(8))) short bf16x8;
typedef __attribute__((ext_vector_type(4))) float f32x4;

// f32 -> bf16 round-to-nearest-even
__device__ __forceinline__ ushort f2bf(float f) {
  unsigned u = __float_as_uint(f);
  return (ushort)((u + 0x7FFFu + ((u >> 16) & 1u)) >> 16);
}

// ---------------------------------------------------------------- threefry
__device__ __forceinline__ void tf_round(unsigned &x0, unsigned &x1, int r) {
  x0 += x1;
  x1 = (x1 << r) | (x1 >> (32 - r));
  x1 ^= x0;
}

__device__ __forceinline__ void threefry2x32(unsigned c0, unsigned c1,
                                             unsigned &o0, unsigned &o1) {
  const unsigned k0 = 0u, k1 = 1234u;
  const unsigned k2 = 0u ^ 1234u ^ 0x1BD11BDAu;
  unsigned x0 = c0 + k0, x1 = c1 + k1;
  tf_round(x0, x1, 13); tf_round(x0, x1, 15); tf_round(x0, x1, 26); tf_round(x0, x1, 6);
  x0 += k1; x1 += k2 + 1u;
  tf_round(x0, x1, 17); tf_round(x0, x1, 29); tf_round(x0, x1, 16); tf_round(x0, x1, 24);
  x0 += k2; x1 += k0 + 2u;
  tf_round(x0, x1, 13); tf_round(x0, x1, 15); tf_round(x0, x1, 26); tf_round(x0, x1, 6);
  x0 += k0; x1 += k1 + 3u;
  tf_round(x0, x1, 17); tf_round(x0, x1, 29); tf_round(x0, x1, 16); tf_round(x0, x1, 24);
  x0 += k1; x1 += k2 + 4u;
  tf_round(x0, x1, 13); tf_round(x0, x1, 15); tf_round(x0, x1, 26); tf_round(x0, x1, 6);
  x0 += k2; x1 += k0 + 5u;
  o0 = x0; o1 = x1;
}

__device__ __forceinline__ float tf_uniform(unsigned bits) {
  return __uint_as_float((bits >> 9) | 0x3F800000u) - 1.0f;
}

__global__ __launch_bounds__(256) void gen_T(float *__restrict__ Tbuf) {
  int i = blockIdx.x * blockDim.x + threadIdx.x;  // 0..12287
  if (i >= NB * TE) return;
  unsigned o0, o1;
  threefry2x32(0u, (unsigned)i, o0, o1);
  Tbuf[i] = tf_uniform(o0 ^ o1) + 0.5f;  // T = u*(1.5-0.5)+0.5
}

// ---------------------------------------------------------------- f32 -> bf16 (8 elems/thread)
__global__ __launch_bounds__(256) void conv_bf16(const float *__restrict__ src,
                                                 ushort *__restrict__ dst) {
  const size_t i = ((size_t)blockIdx.x * 256 + threadIdx.x) * 8;
  float4 a = *(const float4 *)(src + i);
  float4 b = *(const float4 *)(src + i + 4);
  uint4 o;
  o.x = (unsigned)f2bf(a.x) | ((unsigned)f2bf(a.y) << 16);
  o.y = (unsigned)f2bf(a.z) | ((unsigned)f2bf(a.w) << 16);
  o.z = (unsigned)f2bf(b.x) | ((unsigned)f2bf(b.y) << 16);
  o.w = (unsigned)f2bf(b.z) | ((unsigned)f2bf(b.w) << 16);
  *(uint4 *)(dst + i) = o;
}

// ---------------------------------------------------------------- enc -> ench + encT
__global__ __launch_bounds__(256) void conv_encT(const float *__restrict__ enc,
                                                 ushort *__restrict__ ench,
                                                 ushort *__restrict__ encT) {
  const int n = blockIdx.z;
  const int d0 = blockIdx.x * 32;
  const int k0 = blockIdx.y * 32;
  __shared__ ushort t[32][33];
  const int row = threadIdx.x >> 3;      // k within tile
  const int c4 = (threadIdx.x & 7) * 4;  // d within tile
  float4 v = *(const float4 *)(enc + ((size_t)n * TE + k0 + row) * DM + d0 + c4);
  ushort4 e;
  e.x = f2bf(v.x); e.y = f2bf(v.y); e.z = f2bf(v.z); e.w = f2bf(v.w);
  t[row][c4 + 0] = e.x; t[row][c4 + 1] = e.y;
  t[row][c4 + 2] = e.z; t[row][c4 + 3] = e.w;
  *(ushort4 *)(ench + ((size_t)n * TE + k0 + row) * DM + d0 + c4) = e;
  __syncthreads();
  const int dr = threadIdx.x >> 3;       // d within tile
  const int kc = (threadIdx.x & 7) * 4;  // k within tile
  ushort4 o;
  o.x = t[kc + 0][dr]; o.y = t[kc + 1][dr];
  o.z = t[kc + 2][dr]; o.w = t[kc + 3][dr];
  *(ushort4 *)(encT + ((size_t)n * DM + d0 + dr) * TE + k0 + kc) = o;
}

// ---------------------------------------------------------------- bf16 MFMA GEMM
// C[m][n] = scale * sum_k A[m][k]*B[n][k]   (both operands K-contiguous)
// 128x128 tile, 4 waves (2x2), each wave 4x4 16x16x32 MFMA tiles, BK=32.
__global__ __launch_bounds__(256) void gemm_bf16_mfma(
    const ushort *__restrict__ Ag, const ushort *__restrict__ Bg,
    float *__restrict__ Cg, int K, int N, size_t sA, size_t sB, size_t sC,
    float scale) {
  const int nb = blockIdx.z;
  const int n0 = blockIdx.x * 128;
  const int m0 = blockIdx.y * 128;
  const int tid = threadIdx.x;
  const int wave = tid >> 6, lane = tid & 63;
  const int wm = (wave >> 1) * 64, wn = (wave & 1) * 64;
  const int fr = lane & 15, quad = lane >> 4;
  const ushort *A = Ag + nb * sA + (size_t)m0 * K;
  const ushort *B = Bg + nb * sB + (size_t)n0 * K;
  __shared__ ushort As[128 * 32];
  __shared__ ushort Bs[128 * 32];
  f32x4 acc[4][4];
#pragma unroll
  for (int i = 0; i < 4; ++i)
#pragma unroll
    for (int c = 0; c < 4; ++c) acc[i][c] = (f32x4){0.f, 0.f, 0.f, 0.f};

  const int srow = tid >> 1;        // 0..127
  const int scol = (tid & 1) * 16;  // 0 or 16 (ushort offset)
  for (int kb = 0; kb < K; kb += 32) {
    uint4 av0 = *(const uint4 *)(A + (size_t)srow * K + kb + scol);
    uint4 av1 = *(const uint4 *)(A + (size_t)srow * K + kb + scol + 8);
    uint4 bv0 = *(const uint4 *)(B + (size_t)srow * K + kb + scol);
    uint4 bv1 = *(const uint4 *)(B + (size_t)srow * K + kb + scol + 8);
    __syncthreads();
    *(uint4 *)(&As[srow * 32 + scol]) = av0;
    *(uint4 *)(&As[srow * 32 + scol + 8]) = av1;
    *(uint4 *)(&Bs[srow * 32 + scol]) = bv0;
    *(uint4 *)(&Bs[srow * 32 + scol + 8]) = bv1;
    __syncthreads();
    bf16x8 af[4], bfv[4];
#pragma unroll
    for (int i = 0; i < 4; ++i)
      af[i] = *(const bf16x8 *)(&As[(wm + i * 16 + fr) * 32 + quad * 8]);
#pragma unroll
    for (int c = 0; c < 4; ++c)
      bfv[c] = *(const bf16x8 *)(&Bs[(wn + c * 16 + fr) * 32 + quad * 8]);
#pragma unroll
    for (int i = 0; i < 4; ++i)
#pragma unroll
      for (int c = 0; c < 4; ++c)
        acc[i][c] = __builtin_amdgcn_mfma_f32_16x16x32_bf16(af[i], bfv[c],
                                                            acc[i][c], 0, 0, 0);
  }
  float *Cb = Cg + nb * sC;
#pragma unroll
  for (int i = 0; i < 4; ++i)
#pragma unroll
    for (int c = 0; c < 4; ++c)
#pragma unroll
      for (int r = 0; r < 4; ++r)
        Cb[(size_t)(m0 + wm + i * 16 + quad * 4 + r) * N + n0 + wn + c * 16 + fr] =
            acc[i][c][r] * scale;
}

// ---------------------------------------------------------------- softmax
__global__ __launch_bounds__(64) void softmax_rows(
    const float *__restrict__ scores, float *__restrict__ out1) {
  const int row = blockIdx.x;  // n*TD + j
  const int n = row >> 10;
  const int j = row & 1023;
  const int tid = threadIdx.x;
  const float *s = scores + (size_t)row * TE;
  float v[6];
#pragma unroll
  for (int i = 0; i < 6; ++i) v[i] = s[tid + 64 * i];
  float m = v[0];
#pragma unroll
  for (int i = 1; i < 6; ++i) m = fmaxf(m, v[i]);
#pragma unroll
  for (int off = 32; off; off >>= 1) m = fmaxf(m, __shfl_xor(m, off));
  float e[6], sum = 0.f;
#pragma unroll
  for (int i = 0; i < 6; ++i) { e[i] = __expf(v[i] - m); sum += e[i]; }
#pragma unroll
  for (int off = 32; off; off >>= 1) sum += __shfl_xor(sum, off);
  const float r = 1.0f / sum;
  float *dst = out1 + (size_t)n * (2 * TD * TE) + (size_t)j * TE;
#pragma unroll
  for (int i = 0; i < 6; ++i) dst[tid + 64 * i] = e[i] * r;
}

// ---------------------------------------------------------------- cond_prob (parallel)
__global__ __launch_bounds__(256) void cond_prob2(
    const float *__restrict__ scores, const float *__restrict__ Tbuf,
    float *__restrict__ cpT) {
  const int n = blockIdx.z;
  const int j0 = blockIdx.y * 64;
  const int k0 = blockIdx.x * 64;
  const int tid = threadIdx.x;
  __shared__ float eL[82][65];

  {
    const int c4 = (tid & 15) * 4;
    const int r0 = tid >> 4;  // 0..15
    float4 tv = *(const float4 *)(Tbuf + n * TE + k0 + c4);
    const float it0 = 1.0f / tv.x, it1 = 1.0f / tv.y, it2 = 1.0f / tv.z,
                it3 = 1.0f / tv.w;
#pragma unroll
    for (int p = 0; p < 6; ++p) {
      const int r = r0 + p * 16;
      if (r < 82) {
        const int j = j0 + r;
        float4 s;
        if (j < TD) {
          s = *(const float4 *)(scores + ((size_t)n * TD + j) * TE + k0 + c4);
          s.x = __expf(s.x * it0); s.y = __expf(s.y * it1);
          s.z = __expf(s.z * it2); s.w = __expf(s.w * it3);
        } else {
          s = make_float4(0.f, 0.f, 0.f, 0.f);
        }
        eL[r][c4 + 0] = s.x; eL[r][c4 + 1] = s.y;
        eL[r][c4 + 2] = s.z; eL[r][c4 + 3] = s.w;
      }
    }
  }
  __syncthreads();

  const int k = tid & 63;
  const int jl0 = (tid >> 6) * 16;
  float e_r[35];
#pragma unroll
  for (int t = 0; t < 35; ++t) e_r[t] = eL[jl0 + t][k];
  float win = 0.f;
#pragma unroll
  for (int t = 15; t <= 33; ++t) win += e_r[t];
  float cp[16];
#pragma unroll
  for (int jl = 15; jl >= 0; --jl) {
    cp[jl] = e_r[jl] / (win + 1e-8f);
    if (jl > 0) win += e_r[jl - 1] - e_r[jl + 18];
  }
  float *dst = cpT + ((size_t)n * TE + k0 + k) * TD + j0 + jl0;
#pragma unroll
  for (int q = 0; q < 4; ++q)
    *(float4 *)(dst + q * 4) =
        make_float4(cp[q * 4], cp[q * 4 + 1], cp[q * 4 + 2], cp[q * 4 + 3]);
}

// ---------------------------------------------------------------- phase 1 (a scan)
// Single wave per batch n. 16 j per lane. Wave-synchronous LDS exchange of
// q = a*cp (20-float backward halo). No __syncthreads, no HW lgkmcnt(0):
// same-wave DS ops execute in program order; only zero-instruction compiler
// fences order writes<->reads (stops alias-based reordering). The compiler
// inserts a minimal lgkmcnt before the read data's first use and can overlap
// the LDS round trip with independent VALU.
// LDS layout: logical J = j+24 in [0,1048) mapped to phys = J + (J>>4)*4
// (+4 floats of pad per 16) so every ds_read/write_b128 covers all 32 banks.
#define P1PH(J) ((J) + (((J) >> 4) << 2))

#define P1_BODY(CU0, CU1, CU2, CU3, CL0, CL1, CL2, CL3, kk)                   \
  {                                                                           \
    /* prefetch cp column used at step (kk)+3 (column shift: col(k)=k-1) */   \
    const int pc = ((kk) + 2 < TE) ? ((kk) + 2) : (TE - 1);                   \
    const float *pp = cpn + (size_t)pc * TD + j0;                             \
    CL0 = *(const float4 *)(pp);                                              \
    CL1 = *(const float4 *)(pp + 4);                                          \
    CL2 = *(const float4 *)(pp + 8);                                          \
    CL3 = *(const float4 *)(pp + 12);                                         \
    float4 q0 = make_float4(a[0] * CU0.x, a[1] * CU0.y,                       \
                            a[2] * CU0.z, a[3] * CU0.w);                      \
    float4 q1 = make_float4(a[4] * CU1.x, a[5] * CU1.y,                       \
                            a[6] * CU1.z, a[7] * CU1.w);                      \
    float4 q2 = make_float4(a[8] * CU2.x, a[9] * CU2.y,                       \
                            a[10] * CU2.z, a[11] * CU2.w);                    \
    float4 q3 = make_float4(a[12] * CU3.x, a[13] * CU3.y,                     \
                            a[14] * CU3.z, a[15] * CU3.w);                    \
    *(float4 *)(w01p) = q0;                                                   \
    *(float4 *)(w01p + 4) = q1;                                               \
    *(float4 *)(w23p) = q2;                                                   \
    *(float4 *)(w23p + 4) = q3;                                               \
    asm volatile("" ::: "memory"); /* order writes before reads (compiler) */ \
    float4 h1 = *(const float4 *)(rdA);                                       \
    float4 h2 = *(const float4 *)(rdA + 4);                                   \
    float4 h3 = *(const float4 *)(rdA + 8);                                   \
    float4 h4 = *(const float4 *)(rdB);                                       \
    float4 h5 = *(const float4 *)(rdB + 4);                                   \
    asm volatile("" ::: "memory"); /* order reads before next-step writes */  \
    float w[38];                                                              \
    w[4] = h1.x;  w[5] = h1.y;  w[6] = h1.z;  w[7] = h1.w;                    \
    w[8] = h2.x;  w[9] = h2.y;  w[10] = h2.z; w[11] = h2.w;                   \
    w[12] = h3.x; w[13] = h3.y; w[14] = h3.z; w[15] = h3.w;                   \
    w[16] = h4.x; w[17] = h4.y; w[18] = h4.z; w[19] = h4.w;                   \
    w[20] = h5.x; w[21] = h5.y; w[22] = h5.z; w[23] = h5.w;                   \
    w[24] = q0.x; w[25] = q0.y; w[26] = q0.z; w[27] = q0.w;                   \
    w[28] = q1.x; w[29] = q1.y; w[30] = q1.z; w[31] = q1.w;                   \
    w[32] = q2.x; w[33] = q2.y; w[34] = q2.z; w[35] = q2.w;                   \
    w[36] = q3.x; w[37] = q3.y;                                               \
    /* window for j=j0+i is sum w[i+4 .. i+22]; two balanced trees + slides */\
    float t0 = w[4] + w[5], t1 = w[6] + w[7], t2 = w[8] + w[9];               \
    float t3 = w[10] + w[11], t4 = w[12] + w[13], t5 = w[14] + w[15];         \
    float t6 = w[16] + w[17], t7 = w[18] + w[19], t8 = w[20] + w[21];         \
    float s0 = (((t0 + t1) + (t2 + t3)) + ((t4 + t5) + (t6 + t7))) +          \
               (t8 + w[22]);                                                  \
    a[0] = s0;                                                                \
    s0 += w[23] - w[4];  a[1] = s0;                                           \
    s0 += w[24] - w[5];  a[2] = s0;                                           \
    s0 += w[25] - w[6];  a[3] = s0;                                           \
    s0 += w[26] - w[7];  a[4] = s0;                                           \
    s0 += w[27] - w[8];  a[5] = s0;                                           \
    s0 += w[28] - w[9];  a[6] = s0;                                           \
    s0 += w[29] - w[10]; a[7] = s0;                                           \
    float u4 = w[20] + w[21], u5 = w[22] + w[23], u6 = w[24] + w[25];         \
    float u7 = w[26] + w[27], u8 = w[28] + w[29];                             \
    float s1 = (((t4 + t5) + (t6 + t7)) + ((u4 + u5) + (u6 + u7))) +          \
               (u8 + w[30]);                                                  \
    a[8] = s1;                                                                \
    s1 += w[31] - w[12]; a[9] = s1;                                           \
    s1 += w[32] - w[13]; a[10] = s1;                                          \
    s1 += w[33] - w[14]; a[11] = s1;                                          \
    s1 += w[34] - w[15]; a[12] = s1;                                          \
    s1 += w[35] - w[16]; a[13] = s1;                                          \
    s1 += w[36] - w[17]; a[14] = s1;                                          \
    s1 += w[37] - w[18]; a[15] = s1;                                          \
    float *ao = an + (size_t)(kk)*TD + j0;                                    \
    *(float4 *)(ao) = make_float4(a[0], a[1], a[2], a[3]);                    \
    *(float4 *)(ao + 4) = make_float4(a[4], a[5], a[6], a[7]);                \
    *(float4 *)(ao + 8) = make_float4(a[8], a[9], a[10], a[11]);              \
    *(float4 *)(ao + 12) = make_float4(a[12], a[13], a[14], a[15]);           \
  }

__global__ __launch_bounds__(64) void phase1_a(
    const float *__restrict__ cpT, float *__restrict__ aT) {
  const int n = blockIdx.x;
  const int L = threadIdx.x;  // 0..63, one wave
  const int j0 = L * 16;
  __shared__ __align__(16) float qbuf[1320];  // 66 groups * 20 floats

  // zero the 24-float logical pad (j in [-24,-1] -> J in [0,24))
  if (L < 24) qbuf[P1PH(L)] = 0.f;

  const float *cpn = cpT + (size_t)n * TE * TD;
  float *an = aT + (size_t)n * TE * TD;

  // lane-local LDS pointers (all b128-aligned, conflict-free under swizzle)
  // writes: own q[0..15] at J j0+24..j0+39 (phys 20L+28..35, 20L+40..47)
  // reads : halo J j0+4..j0+23 = j j0-20..j0-1 (phys 20L+4..15, 20L+20..27)
  float *w01p = &qbuf[P1PH(j0 + 24)];
  float *w23p = &qbuf[P1PH(j0 + 32)];
  const float *rdA = &qbuf[P1PH(j0) + 4];
  const float *rdB = &qbuf[P1PH(j0 + 16)];

  float a[16];
#pragma unroll
  for (int i = 0; i < 16; ++i) a[i] = 0.f;
  if (L == 0) a[0] = 1.f;

  // prologue: steps 0,1 use cp column 0; step 2 uses column 1
  float4 cpA0, cpA1, cpA2, cpA3, cpB0, cpB1, cpB2, cpB3;
  float4 cpC0, cpC1, cpC2, cpC3, cpD0, cpD1, cpD2, cpD3;
  {
    const float *p0 = cpn + j0;
    cpA0 = *(const float4 *)(p0);
    cpA1 = *(const float4 *)(p0 + 4);
    cpA2 = *(const float4 *)(p0 + 8);
    cpA3 = *(const float4 *)(p0 + 12);
    cpB0 = cpA0; cpB1 = cpA1; cpB2 = cpA2; cpB3 = cpA3;
    const float *p1 = cpn + (size_t)TD + j0;
    cpC0 = *(const float4 *)(p1);
    cpC1 = *(const float4 *)(p1 + 4);
    cpC2 = *(const float4 *)(p1 + 8);
    cpC3 = *(const float4 *)(p1 + 12);
  }

  for (int k = 0; k < TE; k += 4) {  // TE = 384 = 4*96
    P1_BODY(cpA0, cpA1, cpA2, cpA3, cpD0, cpD1, cpD2, cpD3, k);
    P1_BODY(cpB0, cpB1, cpB2, cpB3, cpA0, cpA1, cpA2, cpA3, k + 1);
    P1_BODY(cpC0, cpC1, cpC2, cpC3, cpB0, cpB1, cpB2, cpB3, k + 2);
    P1_BODY(cpD0, cpD1, cpD2, cpD3, cpC0, cpC1, cpC2, cpC3, k + 3);
  }
}

// ---------------------------------------------------------------- phase 2 (B)
__global__ __launch_bounds__(256) void phase2_B(
    const float *__restrict__ cpT, const float *__restrict__ aT,
    float *__restrict__ BT) {
  const int k = blockIdx.x;
  const int n = blockIdx.y;
  const int tid = threadIdx.x;
  const float *cpc = cpT + ((size_t)n * TE + k) * TD;
  const float *ac = aT + ((size_t)n * TE + k) * TD;
  __shared__ float a_l[20 + TD];
  __shared__ float cp_l[TD + 24];
  float4 av = *(const float4 *)(ac + tid * 4);
  *(float4 *)(&a_l[20 + tid * 4]) = av;
  float4 cv = *(const float4 *)(cpc + tid * 4);
  if (tid == 255) cv.w = 0.f;  // cp[1023] never contributes (clamp rule)
  *(float4 *)(&cp_l[tid * 4]) = cv;
  if (tid < 20) a_l[tid] = 0.f;
  if (tid < 24) cp_l[TD + tid] = 0.f;
  __syncthreads();
  const int j0 = tid * 4;
  float ar[21], cpr[21];
#pragma unroll
  for (int t = 0; t < 21; ++t) ar[t] = a_l[20 + j0 - 19 + t];
#pragma unroll
  for (int t = 0; t < 21; ++t) cpr[t] = cp_l[j0 + t];
  float Bo[4];
#pragma unroll
  for (int i = 0; i < 4; ++i) {
    float W = 0.f, acc2 = 0.f;
#pragma unroll
    for (int d = 19; d >= 2; --d) {
      W += cpr[i + 19 - d];
      acc2 = fmaf(ar[19 + i - d], W, acc2);
    }
    Bo[i] = acc2;
  }
  *(float4 *)(BT + ((size_t)n * TE + k) * TD + j0) =
      make_float4(Bo[0], Bo[1], Bo[2], Bo[3]);
}

// ---------------------------------------------------------------- transpose (+ bf16 copy)
__global__ __launch_bounds__(256) void transpose_B(
    const float *__restrict__ BT, float *__restrict__ out1,
    ushort *__restrict__ Bh) {
  __shared__ float tile[32][33];
  const int n = blockIdx.z;
  const int k0 = blockIdx.x * 32;
  const int j0 = blockIdx.y * 32;
  const int tx = threadIdx.x & 31;
  const int ty = threadIdx.x >> 5;  // 0..7
  const float *src = BT + (size_t)n * TE * TD;
#pragma unroll
  for (int r = 0; r < 4; ++r) {
    const int kk = ty + r * 8;
    tile[kk][tx] = src[(size_t)(k0 + kk) * TD + j0 + tx];
  }
  __syncthreads();
  float *dst = out1 + (size_t)n * (2 * TD * TE) + (size_t)TD * TE;
#pragma unroll
  for (int r = 0; r < 4; ++r) {
    const int jj = ty + r * 8;
    const float val = tile[tx][jj];
    dst[(size_t)(j0 + jj) * TE + k0 + tx] = val;
    Bh[((size_t)n * TD + j0 + jj) * TE + k0 + tx] = f2bf(val);
  }
}

// ---------------------------------------------------------------- launch
extern "C" void kernel_launch(void *const *d_in, const int *in_sizes, int n_in,
                              void *d_out, int out_size, void *d_ws,
                              size_t ws_size, hipStream_t stream) {
  (void)in_sizes; (void)n_in; (void)out_size; (void)ws_size;
  const float *enc = (const float *)d_in[0];  // [32][384][512]
  const float *mel = (const float *)d_in[1];  // [32][1024][512]
  float *out = (float *)d_out;
  float *out0 = out;                         // att_out [32][1024][512]
  float *out1 = out + (size_t)NB * TD * DM;  // stacked [32][2][1024][384]

  const size_t SZ = (size_t)NB * TD * TE;    // 12,582,912 floats
  float *ws = (float *)d_ws;
  float *ws_scores = ws;       // scores [n][j][k]; later BT
  float *ws_cpT = ws + SZ;     // cond_prob [n][k][j] (holds ench+melh before)
  float *ws_aT = ws + 2 * SZ;  // a [n][k][j] (holds Bh after phase2)
  float *ws_T = ws + 3 * SZ;   // T [n][k]
  ushort *encTb = (ushort *)(ws + 3 * SZ + NB * TE);  // encT bf16 [n][d][k]
  ushort *ench = (ushort *)ws_cpT;                    // bf16 [n][k][d]
  ushort *melh = (ushort *)ws_cpT + (size_t)NB * TE * DM;  // bf16 [n][j][d]
  ushort *Bh = (ushort *)ws_aT;                       // bf16 [n][j][k]
  float *ws_BT = ws_scores;

  conv_bf16<<<(NB * TD * DM) / (256 * 8), 256, 0, stream>>>(mel, melh);
  conv_encT<<<dim3(DM / 32, TE / 32, NB), 256, 0, stream>>>(enc, ench, encTb);
  gen_T<<<48, 256, 0, stream>>>(ws_T);
  gemm_bf16_mfma<<<dim3(TE / 128, TD / 128, NB), 256, 0, stream>>>(
      melh, ench, ws_scores, DM, TE, (size_t)TD * DM, (size_t)TE * DM,
      (size_t)TD * TE, 0.0441941738241592f);
  softmax_rows<<<NB * TD, 64, 0, stream>>>(ws_scores, out1);
  cond_prob2<<<dim3(TE / 64, TD / 64, NB), 256, 0, stream>>>(ws_scores, ws_T, ws_cpT);
  phase1_a<<<NB, 64, 0, stream>>>(ws_cpT, ws_aT);
  phase2_B<<<dim3(TE, NB), 256, 0, stream>>>(ws_cpT, ws_aT, ws_BT);
  transpose_B<<<dim3(TE / 32, TD / 32, NB), 256, 0, stream>>>(ws_BT, out1, Bh);
  gemm_bf16_mfma<<<dim3(DM / 128, TD / 128, NB), 256, 0, stream>>>(
      Bh, encTb, out0, TE, DM, (size_t)TD * TE, (size_t)DM * TE,
      (size_t)TD * DM, 1.0f);
}